// Round 1
// baseline (649.901 us; speedup 1.0000x reference)
//
#include <hip/hip_runtime.h>

#define S 2048
#define Dh 64
#define NH 16
#define SD (S*Dh)       // 131072 elements per head plane
#define SS (S*S)        // 4194304 elements per head attention matrix

// workspace layout (float offsets)
#define WS_QSUM   0                     // 1024 floats  (16 heads x 64 d)
#define WS_ROWSUM 4096                  // 32768 floats (16 heads x 2048 q)
#define WS_QS     40960                 // 2097152 floats
#define WS_KS     (40960 + 2097152)     // 2097152 floats
// total ws needed: (40960 + 2*2097152)*4 B ~= 16.2 MB

// ---------------- Q softmax over axis=2 (seq axis), per (head, d) column ----
// Pass 1: partial sums of exp over s-chunks, atomicAdd into ws[WS_QSUM].
__global__ void k_qsum(const float* __restrict__ q, float* __restrict__ ws) {
    const int head  = blockIdx.x >> 3;   // 0..15
    const int chunk = blockIdx.x & 7;    // 0..7, each covers 256 s values
    const int t = threadIdx.x;
    const int d = t & 63, sg = t >> 6;   // sg in 0..3
    const float* qh = q + head * SD;
    const int s0 = chunk * 256;
    float acc = 0.f;
#pragma unroll 8
    for (int i = 0; i < 64; ++i) {
        int s = s0 + sg + 4 * i;
        acc += __expf(qh[s * Dh + d]);
    }
    __shared__ float part[4][64];
    part[sg][d] = acc;
    __syncthreads();
    if (sg == 0) {
        float tot = part[0][d] + part[1][d] + part[2][d] + part[3][d];
        atomicAdd(&ws[WS_QSUM + head * 64 + d], tot);
    }
}

// Pass 2: Qs = exp(q) / colsum
__global__ void k_qnorm(const float* __restrict__ q, float* __restrict__ ws) {
    const int gid = blockIdx.x * 256 + threadIdx.x;   // < 524288 float4s
    const int i0 = gid * 4;
    const int head = i0 >> 17;        // / SD
    const int d0 = i0 & 63;
    const float4 qv = ((const float4*)q)[gid];
    const float* qs = &ws[WS_QSUM + head * 64 + d0];
    float4 o;
    o.x = __expf(qv.x) / qs[0];
    o.y = __expf(qv.y) / qs[1];
    o.z = __expf(qv.z) / qs[2];
    o.w = __expf(qv.w) / qs[3];
    ((float4*)&ws[WS_QS])[gid] = o;
}

// ---------------- K softmax over axis=1 (heads axis), 8 values ------------
__global__ void k_ksoft(const float* __restrict__ kin, float* __restrict__ ws) {
    const int gid = blockIdx.x * 256 + threadIdx.x;  // < N*S*Dh = 262144
    const int n = gid >> 17;          // / SD
    const int rem = gid & (SD - 1);
    const float* base = kin + (size_t)n * 8 * SD + rem;
    float x[8];
    float sum = 0.f;
#pragma unroll
    for (int h = 0; h < 8; ++h) { x[h] = __expf(base[(size_t)h * SD]); sum += x[h]; }
    float inv = 1.f / sum;
    float* obase = &ws[WS_KS] + (size_t)n * 8 * SD + rem;
#pragma unroll
    for (int h = 0; h < 8; ++h) obase[(size_t)h * SD] = x[h] * inv;
}

// ---------------- main attention: scores -> exp*mask -> P out + PV --------
// grid: (32 q-tiles, 16 heads), 256 threads. Tq = Tk = 64.
// thread t: tq = t>>4 owns q rows 4*tq..4*tq+3 ; tk = t&15 owns k cols {tk+16j} / d cols 4*tk..4*tk+3
#define LSTR 76   // LDS row stride in floats (19 float4s); 2-way max bank aliasing
__global__ __launch_bounds__(256) void k_attn(
        const float* __restrict__ Qs, const float* __restrict__ Ks,
        const float* __restrict__ V, const int* __restrict__ mask,
        float* __restrict__ ctx, float* __restrict__ A,
        float* __restrict__ rowsum_g) {
    const int qt = blockIdx.x;      // 0..31
    const int head = blockIdx.y;    // 0..15
    const int t = threadIdx.x;
    const int tk = t & 15, tq = t >> 4;
    const int q0 = qt * 64;

    __shared__ float sQ[64 * LSTR];
    __shared__ float sKV[64 * LSTR];
    __shared__ float sP[64 * LSTR];

    // load Q tile
    const float4* Qg4 = (const float4*)(Qs + (size_t)head * SD + (size_t)q0 * Dh);
#pragma unroll
    for (int i = 0; i < 4; ++i) {
        int idx = t + 256 * i;               // 1024 float4s, 16 per row
        int row = idx >> 4, c4 = idx & 15;
        ((float4*)sQ)[row * 19 + c4] = Qg4[idx];
    }

    float4 accv[4];                           // [r] -> ctx acc rows q=4tq+r, d=4tk..4tk+3
#pragma unroll
    for (int r = 0; r < 4; ++r) accv[r] = make_float4(0.f, 0.f, 0.f, 0.f);
    float rs[4] = {0.f, 0.f, 0.f, 0.f};

    for (int kt = 0; kt < 32; ++kt) {
        const int k0 = kt * 64;
        __syncthreads();                      // prev iter done reading sKV/sP
        // load K tile
        const float4* Kg4 = (const float4*)(Ks + (size_t)head * SD + (size_t)k0 * Dh);
#pragma unroll
        for (int i = 0; i < 4; ++i) {
            int idx = t + 256 * i;
            int row = idx >> 4, c4 = idx & 15;
            ((float4*)sKV)[row * 19 + c4] = Kg4[idx];
        }
        __syncthreads();

        // scores: 4q x 4k register block
        float sc[4][4];
#pragma unroll
        for (int r = 0; r < 4; ++r)
#pragma unroll
            for (int j = 0; j < 4; ++j) sc[r][j] = 0.f;
#pragma unroll 4
        for (int d4 = 0; d4 < 16; ++d4) {
            float4 qa0 = ((const float4*)sQ)[(4 * tq + 0) * 19 + d4];
            float4 qa1 = ((const float4*)sQ)[(4 * tq + 1) * 19 + d4];
            float4 qa2 = ((const float4*)sQ)[(4 * tq + 2) * 19 + d4];
            float4 qa3 = ((const float4*)sQ)[(4 * tq + 3) * 19 + d4];
#pragma unroll
            for (int j = 0; j < 4; ++j) {
                float4 kv = ((const float4*)sKV)[(tk + 16 * j) * 19 + d4];
                sc[0][j] += qa0.x * kv.x + qa0.y * kv.y + qa0.z * kv.z + qa0.w * kv.w;
                sc[1][j] += qa1.x * kv.x + qa1.y * kv.y + qa1.z * kv.z + qa1.w * kv.w;
                sc[2][j] += qa2.x * kv.x + qa2.y * kv.y + qa2.z * kv.z + qa2.w * kv.w;
                sc[3][j] += qa3.x * kv.x + qa3.y * kv.y + qa3.z * kv.z + qa3.w * kv.w;
            }
        }
        // mask + exp (scores are tiny; no max-subtraction needed) + rowsum + stage P
#pragma unroll
        for (int r = 0; r < 4; ++r) {
            int qrow = q0 + 4 * tq + r;
#pragma unroll
            for (int j = 0; j < 4; ++j) {
                int k = tk + 16 * j;
                int m = mask[(size_t)qrow * S + k0 + k];
                float p = m ? __expf(sc[r][j]) : 0.f;
                rs[r] += p;
                sP[(4 * tq + r) * LSTR + k] = p;
            }
        }
        __syncthreads();

        // write unnormalized P to the A output region; load V tile into sKV
        const float4* Vg4 = (const float4*)(V + (size_t)head * SD + (size_t)k0 * Dh);
        float4* Abase = (float4*)(A + (size_t)head * SS + (size_t)q0 * S + k0);
#pragma unroll
        for (int i = 0; i < 4; ++i) {
            int idx = t + 256 * i;
            int row = idx >> 4, c4 = idx & 15;
            float4 pv = ((const float4*)sP)[row * 19 + c4];
            Abase[(size_t)row * (S / 4) + c4] = pv;
            ((float4*)sKV)[row * 19 + c4] = Vg4[idx];
        }
        __syncthreads();

        // PV accumulate: ctx[q][d] += P[q][k] * V[k][d]
#pragma unroll 4
        for (int k4 = 0; k4 < 16; ++k4) {
            float4 p0 = ((const float4*)sP)[(4 * tq + 0) * 19 + k4];
            float4 p1 = ((const float4*)sP)[(4 * tq + 1) * 19 + k4];
            float4 p2 = ((const float4*)sP)[(4 * tq + 2) * 19 + k4];
            float4 p3 = ((const float4*)sP)[(4 * tq + 3) * 19 + k4];
            float4 v0 = ((const float4*)sKV)[(4 * k4 + 0) * 19 + tk];
            accv[0].x += p0.x * v0.x; accv[0].y += p0.x * v0.y; accv[0].z += p0.x * v0.z; accv[0].w += p0.x * v0.w;
            accv[1].x += p1.x * v0.x; accv[1].y += p1.x * v0.y; accv[1].z += p1.x * v0.z; accv[1].w += p1.x * v0.w;
            accv[2].x += p2.x * v0.x; accv[2].y += p2.x * v0.y; accv[2].z += p2.x * v0.z; accv[2].w += p2.x * v0.w;
            accv[3].x += p3.x * v0.x; accv[3].y += p3.x * v0.y; accv[3].z += p3.x * v0.z; accv[3].w += p3.x * v0.w;
            float4 v1 = ((const float4*)sKV)[(4 * k4 + 1) * 19 + tk];
            accv[0].x += p0.y * v1.x; accv[0].y += p0.y * v1.y; accv[0].z += p0.y * v1.z; accv[0].w += p0.y * v1.w;
            accv[1].x += p1.y * v1.x; accv[1].y += p1.y * v1.y; accv[1].z += p1.y * v1.z; accv[1].w += p1.y * v1.w;
            accv[2].x += p2.y * v1.x; accv[2].y += p2.y * v1.y; accv[2].z += p2.y * v1.z; accv[2].w += p2.y * v1.w;
            accv[3].x += p3.y * v1.x; accv[3].y += p3.y * v1.y; accv[3].z += p3.y * v1.z; accv[3].w += p3.y * v1.w;
            float4 v2 = ((const float4*)sKV)[(4 * k4 + 2) * 19 + tk];
            accv[0].x += p0.z * v2.x; accv[0].y += p0.z * v2.y; accv[0].z += p0.z * v2.z; accv[0].w += p0.z * v2.w;
            accv[1].x += p1.z * v2.x; accv[1].y += p1.z * v2.y; accv[1].z += p1.z * v2.z; accv[1].w += p1.z * v2.w;
            accv[2].x += p2.z * v2.x; accv[2].y += p2.z * v2.y; accv[2].z += p2.z * v2.z; accv[2].w += p2.z * v2.w;
            accv[3].x += p3.z * v2.x; accv[3].y += p3.z * v2.y; accv[3].z += p3.z * v2.z; accv[3].w += p3.z * v2.w;
            float4 v3 = ((const float4*)sKV)[(4 * k4 + 3) * 19 + tk];
            accv[0].x += p0.w * v3.x; accv[0].y += p0.w * v3.y; accv[0].z += p0.w * v3.z; accv[0].w += p0.w * v3.w;
            accv[1].x += p1.w * v3.x; accv[1].y += p1.w * v3.y; accv[1].z += p1.w * v3.z; accv[1].w += p1.w * v3.w;
            accv[2].x += p2.w * v3.x; accv[2].y += p2.w * v3.y; accv[2].z += p2.w * v3.z; accv[2].w += p2.w * v3.w;
            accv[3].x += p3.w * v3.x; accv[3].y += p3.w * v3.y; accv[3].z += p3.w * v3.z; accv[3].w += p3.w * v3.w;
        }
    }

    // reduce row sums across the 16 tk-lanes (contiguous lanes within a wave)
#pragma unroll
    for (int r = 0; r < 4; ++r) {
        for (int off = 1; off < 16; off <<= 1)
            rs[r] += __shfl_xor(rs[r], off);
    }
    // write row sums for the A-normalization pass
    if (tk == 0) {
#pragma unroll
        for (int r = 0; r < 4; ++r)
            rowsum_g[head * S + q0 + 4 * tq + r] = rs[r];
    }
    // normalized context write
#pragma unroll
    for (int r = 0; r < 4; ++r) {
        float inv = 1.f / rs[r];
        float4 c;
        c.x = accv[r].x * inv; c.y = accv[r].y * inv;
        c.z = accv[r].z * inv; c.w = accv[r].w * inv;
        ((float4*)(ctx + (size_t)head * SD + (size_t)(q0 + 4 * tq + r) * Dh))[tk] = c;
    }
}

// ---------------- normalize A rows --------------------------------------
__global__ void k_scale(float* __restrict__ A, const float* __restrict__ rowsum) {
    const int row = blockIdx.x;               // 0..32767 = head*S + q
    const float inv = 1.f / rowsum[row];
    float4* Arow = (float4*)(A + (size_t)row * S);
    const int t = threadIdx.x;
#pragma unroll
    for (int i = 0; i < 2; ++i) {
        float4 v = Arow[t + 256 * i];
        v.x *= inv; v.y *= inv; v.z *= inv; v.w *= inv;
        Arow[t + 256 * i] = v;
    }
}

extern "C" void kernel_launch(void* const* d_in, const int* in_sizes, int n_in,
                              void* d_out, int out_size, void* d_ws, size_t ws_size,
                              hipStream_t stream) {
    const float* q = (const float*)d_in[0];
    const float* k = (const float*)d_in[1];
    const float* v = (const float*)d_in[2];
    const int* mask = (const int*)d_in[3];
    float* out = (float*)d_out;              // [0, NH*SD) = context ; [NH*SD, +NH*SS) = attn weights
    float* ws = (float*)d_ws;

    hipMemsetAsync(d_ws, 0, 1024 * sizeof(float), stream);   // zero qsum accumulators
    k_qsum<<<128, 256, 0, stream>>>(q, ws);
    k_qnorm<<<2048, 256, 0, stream>>>(q, ws);
    k_ksoft<<<1024, 256, 0, stream>>>(k, ws);
    k_attn<<<dim3(32, 16), 256, 0, stream>>>(ws + WS_QS, ws + WS_KS, v, mask,
                                             out, out + (size_t)NH * SD, ws + WS_ROWSUM);
    k_scale<<<32768, 256, 0, stream>>>(out + (size_t)NH * SD, ws + WS_ROWSUM);
}

// Round 2
// 419.503 us; speedup vs baseline: 1.5492x; 1.5492x over previous
//
#include <hip/hip_runtime.h>

#define S 2048
#define Dh 64
#define NH 16
#define SD (S*Dh)                 // 131072 elements per head plane
#define SSZ ((size_t)S*(size_t)S) // attention matrix elements per head

typedef __attribute__((ext_vector_type(4))) float f32x4;
typedef __attribute__((ext_vector_type(8))) short s16x8;

// workspace layout (byte offsets)
#define WSB_QSUM 0                          // 1024 f32
#define WSB_MASK 4096                       // 65536 uint64 bitmask (512 KB)
#define WSB_QS   (4096 + 524288)            // NH*SD bf16 (4 MB)
#define WSB_KS   (WSB_QS + 4194304)
#define WSB_VT   (WSB_KS + 4194304)         // ends ~12.6 MB

__device__ __forceinline__ ushort f2bf(float x) {
    unsigned u = __builtin_bit_cast(unsigned, x);
    u = (u + 0x7fffu + ((u >> 16) & 1u)) >> 16;
    return (ushort)u;
}

// ---- Q column-softmax denominators: sum_s exp(q[h,s,d]) per (head,d) ------
__global__ void k_qsum(const float* __restrict__ q, float* __restrict__ qsum) {
    const int head  = blockIdx.x >> 3;
    const int chunk = blockIdx.x & 7;
    const int t = threadIdx.x;
    const int d = t & 63, sg = t >> 6;
    const float* qh = q + (size_t)head * SD;
    const int s0 = chunk * 256;
    float acc = 0.f;
#pragma unroll 8
    for (int i = 0; i < 64; ++i) {
        int s = s0 + sg + 4 * i;
        acc += __expf(qh[s * Dh + d]);
    }
    __shared__ float part[4][64];
    part[sg][d] = acc;
    __syncthreads();
    if (sg == 0)
        atomicAdd(&qsum[head * 64 + d], part[0][d] + part[1][d] + part[2][d] + part[3][d]);
}

// ---- Qs = exp(q)/colsum -> bf16 ------------------------------------------
__global__ void k_qnorm(const float* __restrict__ q, const float* __restrict__ qsum,
                        ushort* __restrict__ Qs) {
    const int gid = blockIdx.x * 256 + threadIdx.x;   // 262144 threads x 8 elems
    const int i0 = gid * 8;
    const int head = i0 >> 17;
    const int d0 = i0 & 63;
    const float4 a = ((const float4*)(q + i0))[0];
    const float4 b = ((const float4*)(q + i0))[1];
    const float* qs = qsum + head * 64 + d0;
    s16x8 o;
    o[0] = (short)f2bf(__expf(a.x) / qs[0]);
    o[1] = (short)f2bf(__expf(a.y) / qs[1]);
    o[2] = (short)f2bf(__expf(a.z) / qs[2]);
    o[3] = (short)f2bf(__expf(a.w) / qs[3]);
    o[4] = (short)f2bf(__expf(b.x) / qs[4]);
    o[5] = (short)f2bf(__expf(b.y) / qs[5]);
    o[6] = (short)f2bf(__expf(b.z) / qs[6]);
    o[7] = (short)f2bf(__expf(b.w) / qs[7]);
    *(s16x8*)(Qs + i0) = o;
}

// ---- K softmax over heads axis (8 values) -> bf16 ------------------------
__global__ void k_ksoft(const float* __restrict__ kin, ushort* __restrict__ Ks) {
    const int gid = blockIdx.x * 256 + threadIdx.x;  // N*S*Dh/... = 262144
    const int n = gid >> 17;
    const int rem = gid & (SD - 1);
    const float* base = kin + (size_t)n * 8 * SD + rem;
    float x[8];
    float sum = 0.f;
#pragma unroll
    for (int h = 0; h < 8; ++h) { x[h] = __expf(base[(size_t)h * SD]); sum += x[h]; }
    const float inv = 1.f / sum;
    ushort* ob = Ks + (size_t)n * 8 * SD + rem;
#pragma unroll
    for (int h = 0; h < 8; ++h) ob[(size_t)h * SD] = f2bf(x[h] * inv);
}

// ---- V transpose per head: [k][d] f32 -> Vt[d][k] bf16 -------------------
__global__ void k_vt(const float* __restrict__ V, ushort* __restrict__ Vt) {
    const int head = blockIdx.x >> 5, kt = blockIdx.x & 31;
    const int t = threadIdx.x;
    __shared__ float sv[64 * 68];
    const float4* src = (const float4*)(V + (size_t)head * SD + (size_t)kt * 64 * 64);
#pragma unroll
    for (int i = 0; i < 4; ++i) {
        int idx = t + 256 * i;             // 1024 float4: row=k-local, c4=d/4
        int row = idx >> 4, c4 = idx & 15;
        *(float4*)&sv[row * 68 + c4 * 4] = src[idx];
    }
    __syncthreads();
    const int d = t >> 2, seg = t & 3;     // each thread: 16 k values for one d
    s16x8 v0, v1;
#pragma unroll
    for (int j = 0; j < 8; ++j) v0[j] = (short)f2bf(sv[(seg * 16 + j) * 68 + d]);
#pragma unroll
    for (int j = 0; j < 8; ++j) v1[j] = (short)f2bf(sv[(seg * 16 + 8 + j) * 68 + d]);
    ushort* dst = Vt + (size_t)head * SD + (size_t)d * S + kt * 64 + seg * 16;
    *(s16x8*)dst = v0;
    *(s16x8*)(dst + 8) = v1;
}

// ---- mask int32 [S][S] -> bitmask uint64[S][32] --------------------------
__global__ void k_mask(const int* __restrict__ mask, unsigned long long* __restrict__ bm) {
    const int t = threadIdx.x;
    const int g = blockIdx.x * 4 + (t >> 6);   // wave id 0..1023
    const int lane = t & 63;
    for (int it = 0; it < 64; ++it) {
        int w = g * 64 + it;
        int m = mask[(size_t)w * 64 + lane];
        unsigned long long b = __ballot(m != 0);
        if (lane == 0) bm[w] = b;
    }
}

// ---- fused attention: MFMA QK^T -> exp*mask -> PV ; 2nd pass writes A ----
#define LB 72   // bf16 LDS row stride (64+8): b128 frag reads 2-way max
#define LF 68   // f32 LDS row stride for pass-B staging
__global__ __launch_bounds__(256, 4) void k_attn(
        const ushort* __restrict__ Qs, const ushort* __restrict__ Ks,
        const ushort* __restrict__ Vt, const unsigned long long* __restrict__ bm,
        float* __restrict__ ctx, float* __restrict__ A) {
    const int qt = blockIdx.x, head = blockIdx.y;
    const int q0 = qt * 64;
    const int t = threadIdx.x;
    const int lane = t & 63, wv = t >> 6;
    const int lm = lane & 15, lg = lane >> 4;

    __shared__ __align__(16) char smem[37376];
    ushort* sQ = (ushort*)smem;                                  // [64][72]
    ushort* sK = (ushort*)(smem + 9216);                         // [64][72]
    ushort* sV = (ushort*)(smem + 18432);                        // [64][72] Vt tile
    ushort* sP = (ushort*)(smem + 27648);                        // [64][72]
    unsigned long long* sM = (unsigned long long*)(smem + 36864);// [64]
    float* sPf = (float*)(smem + 18432);                         // pass B: [64][68] aliases sV+sP

    // Q tile -> LDS (persistent)
    {
        const s16x8* src = (const s16x8*)(Qs + (size_t)head * SD + (size_t)q0 * 64);
#pragma unroll
        for (int i = 0; i < 2; ++i) {
            int idx = t + 256 * i;        // 512 x 16B
            int row = idx >> 3, seg = idx & 7;
            *(s16x8*)&sQ[row * LB + seg * 8] = src[idx];
        }
    }

    f32x4 o[4];
#pragma unroll
    for (int c = 0; c < 4; ++c) o[c] = (f32x4){0.f, 0.f, 0.f, 0.f};
    float rs[4] = {0.f, 0.f, 0.f, 0.f};

    const ushort* Kbase = Ks + (size_t)head * SD;
    const ushort* Vbase = Vt + (size_t)head * SD;

    // ---------------- pass A: rowsums + context ----------------
    for (int kt = 0; kt < 32; ++kt) {
        const int k0 = kt * 64;
        __syncthreads();
#pragma unroll
        for (int i = 0; i < 2; ++i) {
            int idx = t + 256 * i;
            int row = idx >> 3, seg = idx & 7;
            *(s16x8*)&sK[row * LB + seg * 8] = *(const s16x8*)(Kbase + (size_t)(k0 + row) * 64 + seg * 8);
            *(s16x8*)&sV[row * LB + seg * 8] = *(const s16x8*)(Vbase + (size_t)row * S + k0 + seg * 8);
        }
        if (t < 64) sM[t] = bm[(size_t)(q0 + t) * 32 + kt];
        __syncthreads();

        f32x4 sc[4];
#pragma unroll
        for (int c = 0; c < 4; ++c) sc[c] = (f32x4){0.f, 0.f, 0.f, 0.f};
#pragma unroll
        for (int h = 0; h < 2; ++h) {
            s16x8 aq = *(const s16x8*)&sQ[(16 * wv + lm) * LB + 32 * h + 8 * lg];
#pragma unroll
            for (int c = 0; c < 4; ++c) {
                s16x8 bk = *(const s16x8*)&sK[(16 * c + lm) * LB + 32 * h + 8 * lg];
                sc[c] = __builtin_amdgcn_mfma_f32_16x16x32_bf16(aq, bk, sc[c], 0, 0, 0);
            }
        }
#pragma unroll
        for (int r = 0; r < 4; ++r) {
            const int rowl = 16 * wv + 4 * lg + r;
            const unsigned long long m64 = sM[rowl];
            float rsum = 0.f;
#pragma unroll
            for (int c = 0; c < 4; ++c) {
                float p = ((m64 >> (16 * c + lm)) & 1ULL) ? __expf(sc[c][r]) : 0.f;
                rsum += p;
                sP[rowl * LB + 16 * c + lm] = f2bf(p);
            }
            rsum += __shfl_xor(rsum, 1);
            rsum += __shfl_xor(rsum, 2);
            rsum += __shfl_xor(rsum, 4);
            rsum += __shfl_xor(rsum, 8);
            rs[r] += rsum;
        }
        __syncthreads();
#pragma unroll
        for (int h = 0; h < 2; ++h) {
            s16x8 ap = *(const s16x8*)&sP[(16 * wv + lm) * LB + 32 * h + 8 * lg];
#pragma unroll
            for (int c = 0; c < 4; ++c) {
                s16x8 bv = *(const s16x8*)&sV[(16 * c + lm) * LB + 32 * h + 8 * lg];
                o[c] = __builtin_amdgcn_mfma_f32_16x16x32_bf16(ap, bv, o[c], 0, 0, 0);
            }
        }
    }

    float inv[4];
#pragma unroll
    for (int r = 0; r < 4; ++r) inv[r] = 1.f / rs[r];

    // normalized context write
#pragma unroll
    for (int r = 0; r < 4; ++r) {
        const int qrow = q0 + 16 * wv + 4 * lg + r;
        float* cb = ctx + (size_t)head * SD + (size_t)qrow * 64;
#pragma unroll
        for (int c = 0; c < 4; ++c) cb[16 * c + lm] = o[c][r] * inv[r];
    }

    // ---------------- pass B: recompute scores, write normalized A --------
    float* Abase = A + (size_t)head * SSZ;
    for (int kt = 0; kt < 32; ++kt) {
        const int k0 = kt * 64;
        __syncthreads();
#pragma unroll
        for (int i = 0; i < 2; ++i) {
            int idx = t + 256 * i;
            int row = idx >> 3, seg = idx & 7;
            *(s16x8*)&sK[row * LB + seg * 8] = *(const s16x8*)(Kbase + (size_t)(k0 + row) * 64 + seg * 8);
        }
        if (t < 64) sM[t] = bm[(size_t)(q0 + t) * 32 + kt];
        __syncthreads();

        f32x4 sc[4];
#pragma unroll
        for (int c = 0; c < 4; ++c) sc[c] = (f32x4){0.f, 0.f, 0.f, 0.f};
#pragma unroll
        for (int h = 0; h < 2; ++h) {
            s16x8 aq = *(const s16x8*)&sQ[(16 * wv + lm) * LB + 32 * h + 8 * lg];
#pragma unroll
            for (int c = 0; c < 4; ++c) {
                s16x8 bk = *(const s16x8*)&sK[(16 * c + lm) * LB + 32 * h + 8 * lg];
                sc[c] = __builtin_amdgcn_mfma_f32_16x16x32_bf16(aq, bk, sc[c], 0, 0, 0);
            }
        }
#pragma unroll
        for (int r = 0; r < 4; ++r) {
            const int rowl = 16 * wv + 4 * lg + r;
            const unsigned long long m64 = sM[rowl];
#pragma unroll
            for (int c = 0; c < 4; ++c) {
                float p = ((m64 >> (16 * c + lm)) & 1ULL) ? __expf(sc[c][r]) * inv[r] : 0.f;
                sPf[rowl * LF + 16 * c + lm] = p;
            }
        }
        __syncthreads();
#pragma unroll
        for (int i = 0; i < 4; ++i) {
            int idx = t + 256 * i;          // 1024 float4
            int row = idx >> 4, c4 = idx & 15;
            *(float4*)&Abase[(size_t)(q0 + row) * S + k0 + c4 * 4] = *(const float4*)&sPf[row * LF + c4 * 4];
        }
    }
}

extern "C" void kernel_launch(void* const* d_in, const int* in_sizes, int n_in,
                              void* d_out, int out_size, void* d_ws, size_t ws_size,
                              hipStream_t stream) {
    const float* q = (const float*)d_in[0];
    const float* k = (const float*)d_in[1];
    const float* v = (const float*)d_in[2];
    const int* mask = (const int*)d_in[3];
    float* out = (float*)d_out;   // [0, NH*SD) ctx ; [NH*SD, +NH*S*S) attn weights
    char* ws = (char*)d_ws;

    float* qsum = (float*)(ws + WSB_QSUM);
    unsigned long long* bm = (unsigned long long*)(ws + WSB_MASK);
    ushort* Qs = (ushort*)(ws + WSB_QS);
    ushort* Ks = (ushort*)(ws + WSB_KS);
    ushort* Vt = (ushort*)(ws + WSB_VT);

    hipMemsetAsync(d_ws, 0, 4096, stream);
    k_qsum<<<128, 256, 0, stream>>>(q, qsum);
    k_mask<<<256, 256, 0, stream>>>(mask, bm);
    k_qnorm<<<1024, 256, 0, stream>>>(q, qsum, Qs);
    k_ksoft<<<1024, 256, 0, stream>>>(k, Ks);
    k_vt<<<512, 256, 0, stream>>>(v, Vt);
    k_attn<<<dim3(32, 16), 256, 0, stream>>>(Qs, Ks, Vt, bm,
                                             out, out + (size_t)NH * SD);
}